// Round 1
// baseline (455.248 us; speedup 1.0000x reference)
//
#include <hip/hip_runtime.h>

typedef short short8 __attribute__((ext_vector_type(8)));
typedef float f32x4 __attribute__((ext_vector_type(4)));
typedef unsigned short u16;
typedef u16 ushort4v __attribute__((ext_vector_type(4)));

__device__ inline u16 f2bf(float f){
  unsigned int u = __builtin_bit_cast(unsigned int, f);
  u = (u + 0x7fffu + ((u >> 16) & 1u)) >> 16;
  return (u16)u;
}

// ---------------- f32 -> bf16 convert (vectorized) ----------------
__global__ void cvt_bf16(const float* __restrict__ in, u16* __restrict__ out, int n4){
  int stride = gridDim.x * blockDim.x;
  for (int i = blockIdx.x * blockDim.x + threadIdx.x; i < n4; i += stride){
    float4 v = ((const float4*)in)[i];
    ushort4v r = { f2bf(v.x), f2bf(v.y), f2bf(v.z), f2bf(v.w) };
    ((ushort4v*)out)[i] = r;
  }
}

// ---------------- bf16 GEMM: C[M][N] = A[M][K] * B[N][K]^T ----------------
// 128x128 tile, BK=32, 4 waves (2x2), each wave 64x64 via 4x4 mfma_16x16x32 frags.
template<int OUT_BF16>
__global__ __launch_bounds__(256) void gemm_bt(const u16* __restrict__ A, const u16* __restrict__ B,
                                               void* __restrict__ Cv, int M, int N, int K){
  __shared__ u16 As[128][40];   // rows padded to 40 bf16 = 80B (16B aligned, bank-spread)
  __shared__ u16 Bs[128][40];
  const int tid  = threadIdx.x;
  const int wave = tid >> 6, lane = tid & 63;
  const int lr = lane & 15, lg = lane >> 4;
  const int wm = wave >> 1, wn = wave & 1;
  const long bm = blockIdx.x * 128L, bn = blockIdx.y * 128L;
  f32x4 acc[4][4] = {};
  for (int k0 = 0; k0 < K; k0 += 32){
    #pragma unroll
    for (int c = 0; c < 2; c++){
      int e = (tid + 256 * c) * 8;
      int row = e >> 5, col = e & 31;
      short8 av = *(const short8*)(A + (bm + row) * (long)K + k0 + col);
      *(short8*)&As[row][col] = av;
      short8 bv = *(const short8*)(B + (bn + row) * (long)K + k0 + col);
      *(short8*)&Bs[row][col] = bv;
    }
    __syncthreads();
    short8 af[4], bfr[4];
    #pragma unroll
    for (int m = 0; m < 4; m++) af[m]  = *(const short8*)&As[wm*64 + m*16 + lr][lg*8];
    #pragma unroll
    for (int n = 0; n < 4; n++) bfr[n] = *(const short8*)&Bs[wn*64 + n*16 + lr][lg*8];
    #pragma unroll
    for (int m = 0; m < 4; m++)
      #pragma unroll
      for (int n = 0; n < 4; n++)
        acc[m][n] = __builtin_amdgcn_mfma_f32_16x16x32_bf16(af[m], bfr[n], acc[m][n], 0, 0, 0);
    __syncthreads();
  }
  #pragma unroll
  for (int m = 0; m < 4; m++){
    #pragma unroll
    for (int n = 0; n < 4; n++){
      #pragma unroll
      for (int r = 0; r < 4; r++){
        long row = bm + wm*64 + m*16 + lg*4 + r;
        long col = bn + wn*64 + n*16 + lr;
        float v = acc[m][n][r];
        if (OUT_BF16) ((u16*)Cv)[row * (long)N + col] = f2bf(v);
        else          ((float*)Cv)[row * (long)N + col] = v;
      }
    }
  }
}

// ---------------- causal flash attention ----------------
// qkv: [B*T][6144] bf16 (q|k|v each 2048 wide). out: [B*T][2048] bf16.
// Block: 256 thr = 4 waves; each wave owns 16 q-rows (Q-tile 64). KV-tile = 32.
__global__ __launch_bounds__(256) void attn_fwd(const u16* __restrict__ qkv, u16* __restrict__ out){
  const int T = 2048, D3 = 6144, D = 2048, HD = 128;
  const int bh = blockIdx.x;            // 0..31
  const int qt = 31 - blockIdx.y;       // heavy tiles first
  const int b = bh >> 4, h = bh & 15;
  const int tid = threadIdx.x, wave = tid >> 6, lane = tid & 63;
  const int lr = lane & 15, lg = lane >> 4;
  const int q0 = qt * 64;
  const int q0w = q0 + wave * 16;

  __shared__ u16 Klds[32][136];   // [key][d], rows 272B
  __shared__ u16 Vlds[128][40];   // transposed: [d][key], rows 80B
  __shared__ u16 Plds[4][16][40]; // per-wave P: [q][key], rows 80B

  const size_t base = (size_t)b * T * D3;

  // Q fragments: lane holds Q[q=lr][d=kk*32+lg*8+j]
  short8 qf[4];
  {
    const u16* qrow = qkv + base + (size_t)(q0w + lr) * D3 + h * HD;
    #pragma unroll
    for (int kk = 0; kk < 4; kk++)
      qf[kk] = *(const short8*)(qrow + kk*32 + lg*8);
  }

  f32x4 o[8] = {};
  float mrow[4], lrow[4];
  #pragma unroll
  for (int r = 0; r < 4; r++){ mrow[r] = -1e30f; lrow[r] = 0.f; }

  const int ntiles = (q0 + 64) >> 5;
  for (int t = 0; t < ntiles; t++){
    const int k0 = t * 32;
    // stage K (row-major) and V (transposed) : 32x128 each
    #pragma unroll
    for (int c = 0; c < 2; c++){
      int e = (tid + 256 * c) * 8;
      int row = e >> 7, col = e & 127;
      const u16* kr = qkv + base + (size_t)(k0 + row) * D3 + D + h * HD + col;
      short8 kvv = *(const short8*)kr;
      *(short8*)&Klds[row][col] = kvv;
      const u16* vr = qkv + base + (size_t)(k0 + row) * D3 + 2 * D + h * HD + col;
      short8 vvv = *(const short8*)vr;
      #pragma unroll
      for (int j = 0; j < 8; j++) Vlds[col + j][row] = (u16)vvv[j];
    }
    __syncthreads();

    if (k0 <= q0w + 15){
      // S = Q K^T  (two 16-key halves)
      f32x4 s[2] = {};
      #pragma unroll
      for (int kh = 0; kh < 2; kh++){
        #pragma unroll
        for (int kk = 0; kk < 4; kk++){
          short8 kfrag = *(const short8*)&Klds[kh*16 + lr][kk*32 + lg*8];
          s[kh] = __builtin_amdgcn_mfma_f32_16x16x32_bf16(qf[kk], kfrag, s[kh], 0, 0, 0);
        }
      }
      const float scale = 0.08838834764831845f; // 1/sqrt(128)
      const bool need_mask = (k0 + 31 > q0w);
      #pragma unroll
      for (int kh = 0; kh < 2; kh++){
        #pragma unroll
        for (int r = 0; r < 4; r++){
          float v = s[kh][r] * scale;
          if (need_mask){
            int key = k0 + kh*16 + lr;
            int qa  = q0w + lg*4 + r;
            if (key > qa) v = -1e30f;
          }
          s[kh][r] = v;
        }
      }
      // online softmax (rows live on 16-lane groups; row = lg*4+r, col = lr)
      float fscale[4];
      #pragma unroll
      for (int r = 0; r < 4; r++){
        float mx = fmaxf(s[0][r], s[1][r]);
        #pragma unroll
        for (int msk = 8; msk >= 1; msk >>= 1)
          mx = fmaxf(mx, __shfl_xor(mx, msk, 64));
        float mnew = fmaxf(mrow[r], mx);
        float f  = __expf(mrow[r] - mnew);
        float p0 = __expf(s[0][r] - mnew);
        float p1 = __expf(s[1][r] - mnew);
        s[0][r] = p0; s[1][r] = p1;
        float rs = p0 + p1;
        #pragma unroll
        for (int msk = 8; msk >= 1; msk >>= 1)
          rs += __shfl_xor(rs, msk, 64);
        lrow[r] = lrow[r] * f + rs;
        mrow[r] = mnew;
        fscale[r] = f;
      }
      #pragma unroll
      for (int dt = 0; dt < 8; dt++)
        #pragma unroll
        for (int r = 0; r < 4; r++)
          o[dt][r] *= fscale[r];
      // P -> LDS (bf16), then read back as PV A-fragment
      #pragma unroll
      for (int kh = 0; kh < 2; kh++)
        #pragma unroll
        for (int r = 0; r < 4; r++)
          Plds[wave][lg*4 + r][kh*16 + lr] = f2bf(s[kh][r]);
      asm volatile("s_waitcnt lgkmcnt(0)" ::: "memory");
      short8 pf = *(const short8*)&Plds[wave][lr][lg*8];
      #pragma unroll
      for (int dt = 0; dt < 8; dt++){
        short8 vf = *(const short8*)&Vlds[dt*16 + lr][lg*8];
        o[dt] = __builtin_amdgcn_mfma_f32_16x16x32_bf16(pf, vf, o[dt], 0, 0, 0);
      }
    }
    __syncthreads();
  }
  // epilogue: O/l -> bf16
  #pragma unroll
  for (int dt = 0; dt < 8; dt++){
    #pragma unroll
    for (int r = 0; r < 4; r++){
      float v = o[dt][r] / lrow[r];
      int qa = q0w + lg*4 + r;
      out[(size_t)(b * T + qa) * D + h * HD + dt*16 + lr] = f2bf(v);
    }
  }
}

extern "C" void kernel_launch(void* const* d_in, const int* in_sizes, int n_in,
                              void* d_out, int out_size, void* d_ws, size_t ws_size,
                              hipStream_t stream) {
  const float* x    = (const float*)d_in[0];   // [2,2048,2048]
  const float* wqkv = (const float*)d_in[1];   // [6144,2048]
  const float* wout = (const float*)d_in[2];   // [2048,2048]
  float* out = (float*)d_out;                  // [2,2048,2048] f32

  u16* ws    = (u16*)d_ws;
  u16* xb    = ws;                    //  8,388,608 elems
  u16* wqkvb = xb + 8388608;          // 12,582,912 elems
  u16* qkvb  = wqkvb + 12582912;      // 25,165,824 elems
  u16* attnb = xb;                    // alias: x dead after GEMM1
  u16* woutb = wqkvb;                 // alias: wqkv dead after GEMM1

  cvt_bf16<<<2048, 256, 0, stream>>>(x,    xb,    8388608 / 4);
  cvt_bf16<<<2048, 256, 0, stream>>>(wqkv, wqkvb, 12582912 / 4);

  // qkv = x @ Wqkv^T : [4096][6144] bf16
  gemm_bt<1><<<dim3(32, 48), 256, 0, stream>>>(xb, wqkvb, qkvb, 4096, 6144, 2048);

  cvt_bf16<<<2048, 256, 0, stream>>>(wout, woutb, 4194304 / 4);

  // attention: [4096][2048] bf16
  attn_fwd<<<dim3(32, 32), 256, 0, stream>>>(qkvb, attnb);

  // y = attn @ Wout^T : [4096][2048] f32
  gemm_bt<0><<<dim3(32, 16), 256, 0, stream>>>(attnb, woutb, out, 4096, 2048, 2048);
}

// Round 3
// 388.477 us; speedup vs baseline: 1.1719x; 1.1719x over previous
//
#include <hip/hip_runtime.h>

typedef short short8 __attribute__((ext_vector_type(8)));
typedef short short4v __attribute__((ext_vector_type(4)));
typedef float f32x4 __attribute__((ext_vector_type(4)));
typedef unsigned short u16;
typedef u16 ushort4v __attribute__((ext_vector_type(4)));

__device__ inline u16 f2bf(float f){
  unsigned int u = __builtin_bit_cast(unsigned int, f);
  u = (u + 0x7fffu + ((u >> 16) & 1u)) >> 16;
  return (u16)u;
}

__device__ inline short8 cat8(short4v a, short4v b){
  short8 r;
  r[0]=a[0]; r[1]=a[1]; r[2]=a[2]; r[3]=a[3];
  r[4]=b[0]; r[5]=b[1]; r[6]=b[2]; r[7]=b[3];
  return r;
}

// ---------------- f32 -> bf16 convert (vectorized) ----------------
__global__ void cvt_bf16(const float* __restrict__ in, u16* __restrict__ out, int n4){
  int stride = gridDim.x * blockDim.x;
  for (int i = blockIdx.x * blockDim.x + threadIdx.x; i < n4; i += stride){
    float4 v = ((const float4*)in)[i];
    ushort4v r = { f2bf(v.x), f2bf(v.y), f2bf(v.z), f2bf(v.w) };
    ((ushort4v*)out)[i] = r;
  }
}

// ---------------- bf16 GEMM: C[M][N] = A[M][K] * B[N][K]^T ----------------
template<int OUT_BF16>
__global__ __launch_bounds__(256) void gemm_bt(const u16* __restrict__ A, const u16* __restrict__ B,
                                               void* __restrict__ Cv, int M, int N, int K){
  __shared__ u16 As[128][40];
  __shared__ u16 Bs[128][40];
  const int tid  = threadIdx.x;
  const int wave = tid >> 6, lane = tid & 63;
  const int lr = lane & 15, lg = lane >> 4;
  const int wm = wave >> 1, wn = wave & 1;
  const long bm = blockIdx.x * 128L, bn = blockIdx.y * 128L;
  f32x4 acc[4][4] = {};
  for (int k0 = 0; k0 < K; k0 += 32){
    #pragma unroll
    for (int c = 0; c < 2; c++){
      int e = (tid + 256 * c) * 8;
      int row = e >> 5, col = e & 31;
      short8 av = *(const short8*)(A + (bm + row) * (long)K + k0 + col);
      *(short8*)&As[row][col] = av;
      short8 bv = *(const short8*)(B + (bn + row) * (long)K + k0 + col);
      *(short8*)&Bs[row][col] = bv;
    }
    __syncthreads();
    short8 af[4], bfr[4];
    #pragma unroll
    for (int m = 0; m < 4; m++) af[m]  = *(const short8*)&As[wm*64 + m*16 + lr][lg*8];
    #pragma unroll
    for (int n = 0; n < 4; n++) bfr[n] = *(const short8*)&Bs[wn*64 + n*16 + lr][lg*8];
    #pragma unroll
    for (int m = 0; m < 4; m++)
      #pragma unroll
      for (int n = 0; n < 4; n++)
        acc[m][n] = __builtin_amdgcn_mfma_f32_16x16x32_bf16(af[m], bfr[n], acc[m][n], 0, 0, 0);
    __syncthreads();
  }
  #pragma unroll
  for (int m = 0; m < 4; m++){
    #pragma unroll
    for (int n = 0; n < 4; n++){
      #pragma unroll
      for (int r = 0; r < 4; r++){
        long row = bm + wm*64 + m*16 + lg*4 + r;
        long col = bn + wn*64 + n*16 + lr;
        float v = acc[m][n][r];
        if (OUT_BF16) ((u16*)Cv)[row * (long)N + col] = f2bf(v);
        else          ((float*)Cv)[row * (long)N + col] = v;
      }
    }
  }
}

// ---------------- causal flash attention ----------------
// qkv: [B*T][6144] bf16. out: [B*T][2048] bf16.
// 256 thr = 4 waves; Q-tile 128 (32 q-rows/wave); KV-tile 64.
// K and V both row-major [64][136] in LDS. PV B-fragments via
// ds_read_b64_tr_b16: lane p fetches V[(p>>4)*8+((p>>2)&3)][(p&3)*4 ..+3]
// (+ kh*32 rows, jh*4 rows, dt*16 cols via byte offsets); the HW 16-lane
// transpose network then delivers lane(r,g),elem j = V[g*8+jh*4+j][dt*16+r].
__global__ __launch_bounds__(256, 2) void attn_fwd(const u16* __restrict__ qkv, u16* __restrict__ out){
  const int T = 2048, D3 = 6144, D = 2048, HD = 128;
  const int bh = blockIdx.x;
  const int qt = (int)gridDim.y - 1 - (int)blockIdx.y;   // heavy tiles first
  const int b = bh >> 4, h = bh & 15;
  const int tid = threadIdx.x, wave = tid >> 6, lane = tid & 63;
  const int lr = lane & 15, lg = lane >> 4;
  const int q0 = qt * 128;
  const int q0w = q0 + wave * 32;

  __shared__ u16 Klds[64][136];
  __shared__ u16 Vlds[64][136];
  __shared__ u16 Plds[4][32][72];

  const size_t base = (size_t)b * T * D3;

  // Q fragments: lane holds Q[q0w+qr*16+lr][kk*32+lg*8+j]
  short8 qf[2][4];
  #pragma unroll
  for (int qr = 0; qr < 2; qr++){
    const u16* qrow = qkv + base + (size_t)(q0w + qr*16 + lr) * D3 + h * HD;
    #pragma unroll
    for (int kk = 0; kk < 4; kk++)
      qf[qr][kk] = *(const short8*)(qrow + kk*32 + lg*8);
  }

  f32x4 o[8][2] = {};
  float mrow[2][4], lrow[2][4];
  #pragma unroll
  for (int qr = 0; qr < 2; qr++)
    #pragma unroll
    for (int r = 0; r < 4; r++){ mrow[qr][r] = -1e30f; lrow[qr][r] = 0.f; }

  // per-lane base for V transpose reads (row-major Vlds)
  const unsigned vtr = (unsigned)(uintptr_t)&Vlds[(lane >> 4) * 8 + ((lane >> 2) & 3)][(lane & 3) * 4];

  const int ntiles = (q0 + 128) >> 6;
  for (int t = 0; t < ntiles; t++){
    const int k0 = t * 64;
    // ---- stage K and V row-major (conflict-free b128 writes) ----
    #pragma unroll
    for (int c = 0; c < 4; c++){
      int e = (tid + 256 * c) * 8;
      int row = e >> 7, col = e & 127;
      const u16* kp = qkv + base + (size_t)(k0 + row) * D3 + D + h * HD + col;
      short8 kv = *(const short8*)kp;
      *(short8*)&Klds[row][col] = kv;
      const u16* vp = qkv + base + (size_t)(k0 + row) * D3 + 2 * D + h * HD + col;
      short8 vv = *(const short8*)vp;
      *(short8*)&Vlds[row][col] = vv;
    }
    __syncthreads();

    if (k0 <= q0w + 31){
      // ---- S = Q K^T ----
      f32x4 s[2][4] = {};
      #pragma unroll
      for (int kh = 0; kh < 4; kh++){
        #pragma unroll
        for (int kk = 0; kk < 4; kk++){
          short8 kfrag = *(const short8*)&Klds[kh*16 + lr][kk*32 + lg*8];
          s[0][kh] = __builtin_amdgcn_mfma_f32_16x16x32_bf16(qf[0][kk], kfrag, s[0][kh], 0, 0, 0);
          s[1][kh] = __builtin_amdgcn_mfma_f32_16x16x32_bf16(qf[1][kk], kfrag, s[1][kh], 0, 0, 0);
        }
      }
      const float scale = 0.08838834764831845f; // 1/sqrt(128)
      const bool need_mask = (k0 + 63 > q0w);
      #pragma unroll
      for (int kh = 0; kh < 4; kh++){
        int key = k0 + kh*16 + lr;
        #pragma unroll
        for (int qr = 0; qr < 2; qr++){
          #pragma unroll
          for (int r = 0; r < 4; r++){
            float v = s[qr][kh][r] * scale;
            if (need_mask && key > q0w + qr*16 + lg*4 + r) v = -1e30f;
            s[qr][kh][r] = v;
          }
        }
      }
      // ---- online softmax (row = lg*4+r per 16-lane group, col = lr) ----
      float fs[2][4];
      #pragma unroll
      for (int qr = 0; qr < 2; qr++){
        #pragma unroll
        for (int r = 0; r < 4; r++){
          float mx = fmaxf(fmaxf(s[qr][0][r], s[qr][1][r]), fmaxf(s[qr][2][r], s[qr][3][r]));
          #pragma unroll
          for (int msk = 8; msk >= 1; msk >>= 1)
            mx = fmaxf(mx, __shfl_xor(mx, msk, 64));
          float mnew = fmaxf(mrow[qr][r], mx);
          float f = __expf(mrow[qr][r] - mnew);
          float p0 = __expf(s[qr][0][r] - mnew);
          float p1 = __expf(s[qr][1][r] - mnew);
          float p2 = __expf(s[qr][2][r] - mnew);
          float p3 = __expf(s[qr][3][r] - mnew);
          s[qr][0][r] = p0; s[qr][1][r] = p1; s[qr][2][r] = p2; s[qr][3][r] = p3;
          float rs = (p0 + p1) + (p2 + p3);
          #pragma unroll
          for (int msk = 8; msk >= 1; msk >>= 1)
            rs += __shfl_xor(rs, msk, 64);
          lrow[qr][r] = lrow[qr][r] * f + rs;
          mrow[qr][r] = mnew;
          fs[qr][r] = f;
        }
      }
      #pragma unroll
      for (int dt = 0; dt < 8; dt++)
        #pragma unroll
        for (int qr = 0; qr < 2; qr++)
          #pragma unroll
          for (int r = 0; r < 4; r++)
            o[dt][qr][r] *= fs[qr][r];
      // ---- P -> LDS (bf16) ----
      #pragma unroll
      for (int qr = 0; qr < 2; qr++)
        #pragma unroll
        for (int kh = 0; kh < 4; kh++)
          #pragma unroll
          for (int r = 0; r < 4; r++)
            Plds[wave][qr*16 + lg*4 + r][kh*16 + lr] = f2bf(s[qr][kh][r]);
      asm volatile("s_waitcnt lgkmcnt(0)" ::: "memory");
      __builtin_amdgcn_sched_barrier(0);
      short8 pf[2][2];
      #pragma unroll
      for (int qr = 0; qr < 2; qr++)
        #pragma unroll
        for (int kp2 = 0; kp2 < 2; kp2++)
          pf[qr][kp2] = *(const short8*)&Plds[wave][qr*16 + lr][kp2*32 + lg*8];
      // drain compiler DS ops so our counted asm waits below are exact
      asm volatile("s_waitcnt lgkmcnt(0)" ::: "memory");
      __builtin_amdgcn_sched_barrier(0);

      // ---- PV with pipelined hardware-transpose V reads ----
      // offsets (bytes, pitch 272): jh -> 1088 (4 rows), kh -> 8704 (32 rows)
      short4v vf[2][2][2];  // [buf][kh][jh]
      #define TR4(BUF, PTR) \
        asm volatile("ds_read_b64_tr_b16 %0, %1"             : "=v"(vf[BUF][0][0]) : "v"(PTR)); \
        asm volatile("ds_read_b64_tr_b16 %0, %1 offset:1088" : "=v"(vf[BUF][0][1]) : "v"(PTR)); \
        asm volatile("ds_read_b64_tr_b16 %0, %1 offset:8704" : "=v"(vf[BUF][1][0]) : "v"(PTR)); \
        asm volatile("ds_read_b64_tr_b16 %0, %1 offset:9792" : "=v"(vf[BUF][1][1]) : "v"(PTR));
      TR4(0, vtr)
      #pragma unroll
      for (int dt = 0; dt < 8; dt++){
        if (dt < 7){
          unsigned pn = vtr + (unsigned)((dt + 1) * 32);
          TR4((dt + 1) & 1, pn)
          asm volatile("s_waitcnt lgkmcnt(4)" ::: "memory");
        } else {
          asm volatile("s_waitcnt lgkmcnt(0)" ::: "memory");
        }
        __builtin_amdgcn_sched_barrier(0);
        short8 v0 = cat8(vf[dt & 1][0][0], vf[dt & 1][0][1]);
        short8 v1 = cat8(vf[dt & 1][1][0], vf[dt & 1][1][1]);
        o[dt][0] = __builtin_amdgcn_mfma_f32_16x16x32_bf16(pf[0][0], v0, o[dt][0], 0, 0, 0);
        o[dt][1] = __builtin_amdgcn_mfma_f32_16x16x32_bf16(pf[1][0], v0, o[dt][1], 0, 0, 0);
        o[dt][0] = __builtin_amdgcn_mfma_f32_16x16x32_bf16(pf[0][1], v1, o[dt][0], 0, 0, 0);
        o[dt][1] = __builtin_amdgcn_mfma_f32_16x16x32_bf16(pf[1][1], v1, o[dt][1], 0, 0, 0);
      }
      #undef TR4
    }
    __syncthreads();
  }
  // ---- epilogue ----
  #pragma unroll
  for (int qr = 0; qr < 2; qr++){
    float rl[4];
    #pragma unroll
    for (int r = 0; r < 4; r++) rl[r] = 1.0f / lrow[qr][r];
    #pragma unroll
    for (int dt = 0; dt < 8; dt++){
      #pragma unroll
      for (int r = 0; r < 4; r++){
        float v = o[dt][qr][r] * rl[r];
        int qa = q0w + qr*16 + lg*4 + r;
        out[(size_t)(b * T + qa) * D + h * HD + dt*16 + lr] = f2bf(v);
      }
    }
  }
}

extern "C" void kernel_launch(void* const* d_in, const int* in_sizes, int n_in,
                              void* d_out, int out_size, void* d_ws, size_t ws_size,
                              hipStream_t stream) {
  const float* x    = (const float*)d_in[0];   // [2,2048,2048]
  const float* wqkv = (const float*)d_in[1];   // [6144,2048]
  const float* wout = (const float*)d_in[2];   // [2048,2048]
  float* out = (float*)d_out;                  // [2,2048,2048] f32

  u16* ws    = (u16*)d_ws;
  u16* xb    = ws;                    //  8,388,608 elems
  u16* wqkvb = xb + 8388608;          // 12,582,912 elems
  u16* qkvb  = wqkvb + 12582912;      // 25,165,824 elems
  u16* attnb = xb;                    // alias: x dead after GEMM1
  u16* woutb = wqkvb;                 // alias: wqkv dead after GEMM1

  cvt_bf16<<<2048, 256, 0, stream>>>(x,    xb,    8388608 / 4);
  cvt_bf16<<<2048, 256, 0, stream>>>(wqkv, wqkvb, 12582912 / 4);

  // qkv = x @ Wqkv^T : [4096][6144] bf16
  gemm_bt<1><<<dim3(32, 48), 256, 0, stream>>>(xb, wqkvb, qkvb, 4096, 6144, 2048);

  cvt_bf16<<<2048, 256, 0, stream>>>(wout, woutb, 4194304 / 4);

  // attention: [4096][2048] bf16
  attn_fwd<<<dim3(32, 16), 256, 0, stream>>>(qkvb, attnb);

  // y = attn @ Wout^T : [4096][2048] f32
  gemm_bt<0><<<dim3(32, 16), 256, 0, stream>>>(attnb, woutb, out, 4096, 2048, 2048);
}

// Round 4
// 275.618 us; speedup vs baseline: 1.6517x; 1.4095x over previous
//
#include <hip/hip_runtime.h>

typedef short short8 __attribute__((ext_vector_type(8)));
typedef short short4v __attribute__((ext_vector_type(4)));
typedef float f32x4 __attribute__((ext_vector_type(4)));
typedef unsigned short u16;
typedef u16 ushort4v __attribute__((ext_vector_type(4)));

__device__ inline u16 f2bf(float f){
  unsigned int u = __builtin_bit_cast(unsigned int, f);
  u = (u + 0x7fffu + ((u >> 16) & 1u)) >> 16;
  return (u16)u;
}

__device__ inline short8 cat8(short4v a, short4v b){
  short8 r;
  r[0]=a[0]; r[1]=a[1]; r[2]=a[2]; r[3]=a[3];
  r[4]=b[0]; r[5]=b[1]; r[6]=b[2]; r[7]=b[3];
  return r;
}

// async global->LDS, 16B per lane. lds dest = wave-uniform base + lane*16.
__device__ inline void gload_lds16(const void* g, unsigned lds_addr){
  __builtin_amdgcn_global_load_lds((__attribute__((address_space(1))) void*)(uintptr_t)g,
                                   (__attribute__((address_space(3))) void*)(uintptr_t)lds_addr,
                                   16, 0, 0);
}

// ---------------- f32 -> bf16 convert (vectorized) ----------------
__global__ void cvt_bf16(const float* __restrict__ in, u16* __restrict__ out, int n4){
  int stride = gridDim.x * blockDim.x;
  for (int i = blockIdx.x * blockDim.x + threadIdx.x; i < n4; i += stride){
    float4 v = ((const float4*)in)[i];
    ushort4v r = { f2bf(v.x), f2bf(v.y), f2bf(v.z), f2bf(v.w) };
    ((ushort4v*)out)[i] = r;
  }
}

// ---------------- bf16 GEMM: C[M][N] = A[M][K] * B[N][K]^T ----------------
// m97 structure: 128x128 tile, BK=64, global_load_lds(16B) staging into
// LINEAR LDS with pre-swizzled global source (XOR of 16B-slot index with
// row&7); ds_read applies the same XOR -> 2-way banks (free).
template<int OUT_BF16>
__global__ __launch_bounds__(256) void gemm_bt(const u16* __restrict__ A, const u16* __restrict__ B,
                                               void* __restrict__ Cv, int M, int N, int K){
  __shared__ u16 As[128 * 64];
  __shared__ u16 Bs[128 * 64];
  const int tid  = threadIdx.x;
  const int wave = tid >> 6, lane = tid & 63;
  const int lr = lane & 15, lg = lane >> 4;
  const int wm = wave >> 1, wn = wave & 1;
  const long bm = blockIdx.x * 128L, bn = blockIdx.y * 128L;
  const unsigned asb = (unsigned)(uintptr_t)As;
  const unsigned bsb = (unsigned)(uintptr_t)Bs;

  // staging geometry: wave w rows [32w,32w+32), call c covers rows +8c..+8c+7
  // lane l -> row = 32w+8c+(l>>3), phys 16B-slot = l&7,
  // logical slot = (l&7) ^ (l>>3)  (inverse swizzle on the SOURCE)
  const int  srow = wave * 32 + (lane >> 3);
  const int  scol = ((lane & 7) ^ (lane >> 3)) * 8;
  const u16* aptr = A + (bm + srow) * (long)K + scol;
  const u16* bptr = B + (bn + srow) * (long)K + scol;
  const unsigned sdst = (unsigned)(wave * 4096);   // + 1024*c ; HW adds lane*16

  f32x4 acc[4][4] = {};
  for (int k0 = 0; k0 < K; k0 += 64){
    #pragma unroll
    for (int c = 0; c < 4; c++){
      gload_lds16(aptr + (size_t)(8 * c) * K + k0, asb + sdst + 1024u * c);
      gload_lds16(bptr + (size_t)(8 * c) * K + k0, bsb + sdst + 1024u * c);
    }
    __syncthreads();   // compiler drains vmcnt before barrier
    #pragma unroll
    for (int kk = 0; kk < 2; kk++){
      short8 af[4], bfr[4];
      #pragma unroll
      for (int m = 0; m < 4; m++){
        int row = wm * 64 + m * 16 + lr;
        int phys = (kk * 4 + lg) ^ (row & 7);
        af[m] = *(const short8*)&As[row * 64 + phys * 8];
      }
      #pragma unroll
      for (int n = 0; n < 4; n++){
        int row = wn * 64 + n * 16 + lr;
        int phys = (kk * 4 + lg) ^ (row & 7);
        bfr[n] = *(const short8*)&Bs[row * 64 + phys * 8];
      }
      #pragma unroll
      for (int m = 0; m < 4; m++)
        #pragma unroll
        for (int n = 0; n < 4; n++)
          acc[m][n] = __builtin_amdgcn_mfma_f32_16x16x32_bf16(af[m], bfr[n], acc[m][n], 0, 0, 0);
    }
    __syncthreads();
  }
  #pragma unroll
  for (int m = 0; m < 4; m++){
    #pragma unroll
    for (int n = 0; n < 4; n++){
      #pragma unroll
      for (int r = 0; r < 4; r++){
        long row = bm + wm*64 + m*16 + lg*4 + r;
        long col = bn + wn*64 + n*16 + lr;
        float v = acc[m][n][r];
        if (OUT_BF16) ((u16*)Cv)[row * (long)N + col] = f2bf(v);
        else          ((float*)Cv)[row * (long)N + col] = v;
      }
    }
  }
}

// ---------------- causal flash attention ----------------
// 512 thr = 8 waves; Q-tile 128 (16 rows/wave); KV-tile 64.
// Each block processes TWO q-tiles (qt = 15-pr then pr) -> uniform work
// (34 KV-tiles/block), grid 32 x 8 = 256 blocks. T14 async reg staging.
__global__ __launch_bounds__(512, 2) void attn_fwd(const u16* __restrict__ qkv, u16* __restrict__ out){
  const int T = 2048, D3 = 6144, D = 2048, HD = 128;
  const int bh = blockIdx.x;
  const int pr = blockIdx.y;            // 0..7
  const int b = bh >> 4, h = bh & 15;
  const int tid = threadIdx.x, wave = tid >> 6, lane = tid & 63;
  const int lr = lane & 15, lg = lane >> 4;

  __shared__ u16 Klds[64][136];
  __shared__ u16 Vlds[64][136];
  __shared__ u16 Plds[8][16][72];

  const size_t base = (size_t)b * T * D3;
  const unsigned vtr = (unsigned)(uintptr_t)&Vlds[(lane >> 4) * 8 + ((lane >> 2) & 3)][(lane & 3) * 4];

  // staging map: 512 thr, sweep c in {0,1}: row = (tid>>4)+32c, col = (tid&15)*8
  const int srow = tid >> 4;
  const int scol = (tid & 15) * 8;
  const u16* kgp = qkv + base + (size_t)srow * D3 + D + h * HD + scol;
  const u16* vgp = kgp + D;   // V section is +2048 elems after K

  for (int half = 0; half < 2; half++){
    const int qt = half ? pr : (15 - pr);
    const int q0 = qt * 128;
    const int q0w = q0 + wave * 16;

    short8 qf[4];
    {
      const u16* qrow = qkv + base + (size_t)(q0w + lr) * D3 + h * HD;
      #pragma unroll
      for (int kk = 0; kk < 4; kk++)
        qf[kk] = *(const short8*)(qrow + kk*32 + lg*8);
    }

    f32x4 o[8] = {};
    float mrow[4], lrw[4];
    #pragma unroll
    for (int r = 0; r < 4; r++){ mrow[r] = -1e30f; lrw[r] = 0.f; }

    const int ntiles = (q0 + 128) >> 6;
    short8 kreg[2], vreg[2];
    #pragma unroll
    for (int c = 0; c < 2; c++){
      kreg[c] = *(const short8*)(kgp + (size_t)(32 * c) * D3);
      vreg[c] = *(const short8*)(vgp + (size_t)(32 * c) * D3);
    }

    for (int t = 0; t < ntiles; t++){
      const int k0 = t * 64;
      __syncthreads();                       // prior tile's LDS reads done
      #pragma unroll
      for (int c = 0; c < 2; c++){
        *(short8*)&Klds[srow + 32*c][scol] = kreg[c];
        *(short8*)&Vlds[srow + 32*c][scol] = vreg[c];
      }
      __syncthreads();                       // tile staged
      if (t + 1 < ntiles){                   // T14: issue next loads early
        const u16* kn = kgp + (size_t)(k0 + 64) * D3;
        const u16* vn = vgp + (size_t)(k0 + 64) * D3;
        #pragma unroll
        for (int c = 0; c < 2; c++){
          kreg[c] = *(const short8*)(kn + (size_t)(32 * c) * D3);
          vreg[c] = *(const short8*)(vn + (size_t)(32 * c) * D3);
        }
      }

      if (k0 <= q0w + 15){
        // ---- S = Q K^T ----
        f32x4 s[4] = {};
        #pragma unroll
        for (int kh = 0; kh < 4; kh++){
          #pragma unroll
          for (int kk = 0; kk < 4; kk++){
            short8 kfrag = *(const short8*)&Klds[kh*16 + lr][kk*32 + lg*8];
            s[kh] = __builtin_amdgcn_mfma_f32_16x16x32_bf16(qf[kk], kfrag, s[kh], 0, 0, 0);
          }
        }
        const float scale = 0.08838834764831845f; // 1/sqrt(128)
        const bool need_mask = (k0 + 63 > q0w);
        #pragma unroll
        for (int kh = 0; kh < 4; kh++){
          int key = k0 + kh*16 + lr;
          #pragma unroll
          for (int r = 0; r < 4; r++){
            float v = s[kh][r] * scale;
            if (need_mask && key > q0w + lg*4 + r) v = -1e30f;
            s[kh][r] = v;
          }
        }
        // ---- online softmax (row = lg*4+r per 16-lane group, col = lr) ----
        float fs[4];
        #pragma unroll
        for (int r = 0; r < 4; r++){
          float mx = fmaxf(fmaxf(s[0][r], s[1][r]), fmaxf(s[2][r], s[3][r]));
          #pragma unroll
          for (int msk = 8; msk >= 1; msk >>= 1)
            mx = fmaxf(mx, __shfl_xor(mx, msk, 64));
          float mnew = fmaxf(mrow[r], mx);
          float f = __expf(mrow[r] - mnew);
          float p0 = __expf(s[0][r] - mnew);
          float p1 = __expf(s[1][r] - mnew);
          float p2 = __expf(s[2][r] - mnew);
          float p3 = __expf(s[3][r] - mnew);
          s[0][r] = p0; s[1][r] = p1; s[2][r] = p2; s[3][r] = p3;
          float rs = (p0 + p1) + (p2 + p3);
          #pragma unroll
          for (int msk = 8; msk >= 1; msk >>= 1)
            rs += __shfl_xor(rs, msk, 64);
          lrw[r] = lrw[r] * f + rs;
          mrow[r] = mnew;
          fs[r] = f;
        }
        #pragma unroll
        for (int dt = 0; dt < 8; dt++)
          #pragma unroll
          for (int r = 0; r < 4; r++)
            o[dt][r] *= fs[r];
        // ---- P -> LDS (bf16) ----
        #pragma unroll
        for (int kh = 0; kh < 4; kh++)
          #pragma unroll
          for (int r = 0; r < 4; r++)
            Plds[wave][lg*4 + r][kh*16 + lr] = f2bf(s[kh][r]);
        asm volatile("s_waitcnt lgkmcnt(0)" ::: "memory");
        __builtin_amdgcn_sched_barrier(0);
        short8 pf[2];
        #pragma unroll
        for (int kp2 = 0; kp2 < 2; kp2++)
          pf[kp2] = *(const short8*)&Plds[wave][lr][kp2*32 + lg*8];
        asm volatile("s_waitcnt lgkmcnt(0)" ::: "memory");
        __builtin_amdgcn_sched_barrier(0);

        // ---- PV with pipelined hardware-transpose V reads ----
        short4v vf[2][2][2];  // [buf][kh][jh]
        #define TR4(BUF, PTR) \
          asm volatile("ds_read_b64_tr_b16 %0, %1"             : "=v"(vf[BUF][0][0]) : "v"(PTR)); \
          asm volatile("ds_read_b64_tr_b16 %0, %1 offset:1088" : "=v"(vf[BUF][0][1]) : "v"(PTR)); \
          asm volatile("ds_read_b64_tr_b16 %0, %1 offset:8704" : "=v"(vf[BUF][1][0]) : "v"(PTR)); \
          asm volatile("ds_read_b64_tr_b16 %0, %1 offset:9792" : "=v"(vf[BUF][1][1]) : "v"(PTR));
        TR4(0, vtr)
        #pragma unroll
        for (int dt = 0; dt < 8; dt++){
          if (dt < 7){
            unsigned pn = vtr + (unsigned)((dt + 1) * 32);
            TR4((dt + 1) & 1, pn)
            asm volatile("s_waitcnt lgkmcnt(4)" ::: "memory");
          } else {
            asm volatile("s_waitcnt lgkmcnt(0)" ::: "memory");
          }
          __builtin_amdgcn_sched_barrier(0);
          short8 v0 = cat8(vf[dt & 1][0][0], vf[dt & 1][0][1]);
          short8 v1 = cat8(vf[dt & 1][1][0], vf[dt & 1][1][1]);
          o[dt] = __builtin_amdgcn_mfma_f32_16x16x32_bf16(pf[0], v0, o[dt], 0, 0, 0);
          o[dt] = __builtin_amdgcn_mfma_f32_16x16x32_bf16(pf[1], v1, o[dt], 0, 0, 0);
        }
        #undef TR4
      }
    }
    // ---- epilogue for this half ----
    float rl[4];
    #pragma unroll
    for (int r = 0; r < 4; r++) rl[r] = 1.0f / lrw[r];
    #pragma unroll
    for (int dt = 0; dt < 8; dt++){
      #pragma unroll
      for (int r = 0; r < 4; r++){
        float v = o[dt][r] * rl[r];
        int qa = q0w + lg*4 + r;
        out[(size_t)(b * T + qa) * D + h * HD + dt*16 + lr] = f2bf(v);
      }
    }
  }
}

extern "C" void kernel_launch(void* const* d_in, const int* in_sizes, int n_in,
                              void* d_out, int out_size, void* d_ws, size_t ws_size,
                              hipStream_t stream) {
  const float* x    = (const float*)d_in[0];   // [2,2048,2048]
  const float* wqkv = (const float*)d_in[1];   // [6144,2048]
  const float* wout = (const float*)d_in[2];   // [2048,2048]
  float* out = (float*)d_out;                  // [2,2048,2048] f32

  u16* ws    = (u16*)d_ws;
  u16* xb    = ws;                    //  8,388,608 elems
  u16* wqkvb = xb + 8388608;          // 12,582,912 elems
  u16* qkvb  = wqkvb + 12582912;      // 25,165,824 elems
  u16* attnb = xb;                    // alias: x dead after GEMM1
  u16* woutb = wqkvb;                 // alias: wqkv dead after GEMM1

  cvt_bf16<<<2048, 256, 0, stream>>>(x,    xb,    8388608 / 4);
  cvt_bf16<<<2048, 256, 0, stream>>>(wqkv, wqkvb, 12582912 / 4);

  // qkv = x @ Wqkv^T : [4096][6144] bf16
  gemm_bt<1><<<dim3(32, 48), 256, 0, stream>>>(xb, wqkvb, qkvb, 4096, 6144, 2048);

  cvt_bf16<<<2048, 256, 0, stream>>>(wout, woutb, 4194304 / 4);

  // attention: [4096][2048] bf16
  attn_fwd<<<dim3(32, 8), 512, 0, stream>>>(qkvb, attnb);

  // y = attn @ Wout^T : [4096][2048] f32
  gemm_bt<0><<<dim3(32, 16), 256, 0, stream>>>(attnb, woutb, out, 4096, 2048, 2048);
}

// Round 5
// 268.484 us; speedup vs baseline: 1.6956x; 1.0266x over previous
//
#include <hip/hip_runtime.h>

typedef short short8 __attribute__((ext_vector_type(8)));
typedef short short4v __attribute__((ext_vector_type(4)));
typedef float f32x4 __attribute__((ext_vector_type(4)));
typedef unsigned short u16;
typedef u16 ushort4v __attribute__((ext_vector_type(4)));

__device__ inline u16 f2bf(float f){
  unsigned int u = __builtin_bit_cast(unsigned int, f);
  u = (u + 0x7fffu + ((u >> 16) & 1u)) >> 16;
  return (u16)u;
}

__device__ inline short8 cat8(short4v a, short4v b){
  short8 r;
  r[0]=a[0]; r[1]=a[1]; r[2]=a[2]; r[3]=a[3];
  r[4]=b[0]; r[5]=b[1]; r[6]=b[2]; r[7]=b[3];
  return r;
}

// async global->LDS, 16B per lane. lds dest = wave-uniform base + lane*16.
__device__ inline void gload_lds16(const void* g, unsigned lds_addr){
  __builtin_amdgcn_global_load_lds((__attribute__((address_space(1))) void*)(uintptr_t)g,
                                   (__attribute__((address_space(3))) void*)(uintptr_t)lds_addr,
                                   16, 0, 0);
}

// ---------------- f32 -> bf16 convert (vectorized) ----------------
__global__ void cvt_bf16(const float* __restrict__ in, u16* __restrict__ out, int n4){
  int stride = gridDim.x * blockDim.x;
  for (int i = blockIdx.x * blockDim.x + threadIdx.x; i < n4; i += stride){
    float4 v = ((const float4*)in)[i];
    ushort4v r = { f2bf(v.x), f2bf(v.y), f2bf(v.z), f2bf(v.w) };
    ((ushort4v*)out)[i] = r;
  }
}

// ---------------- bf16 GEMM: C[M][N] = A[M][K] * B[N][K]^T ----------------
// BM=128, BN=256, BK=64, 512 thr / 8 waves (wm 0..1 x wn 0..3).
// Double-buffered LDS; counted s_waitcnt vmcnt(6) + raw s_barrier so the
// next tile's global_load_lds stay in flight across the barrier (T3/T4).
// XOR swizzle: LDS[row][phys p] = global[row][p ^ (row&7)] (16B slots).
template<int OUT_BF16>
__global__ __launch_bounds__(512, 2) void gemm_bt2(const u16* __restrict__ A, const u16* __restrict__ B,
                                                   void* __restrict__ Cv, int M, int N, int K){
  __shared__ u16 lds[2][24576];   // per buf: A 128x64 (8192) then B 256x64 (16384)
  const int tid = threadIdx.x, wave = tid >> 6, lane = tid & 63;
  const int lr = lane & 15, lg = lane >> 4;
  const int wm = wave >> 2, wn = wave & 3;
  const long bm = blockIdx.x * 128L, bn = blockIdx.y * 256L;
  const int l3 = lane >> 3, l7 = lane & 7;

  // staging: per sweep 64 rows; wave w covers rows w*8..w*8+7; phys slot = l7;
  // source col slot (inverse swizzle) = l7 ^ (row&7) = l7 ^ l3.
  const u16* asrc = A + (bm + wave * 8 + l3) * (long)K + (l7 ^ l3) * 8;
  const u16* bsrc = B + (bn + wave * 8 + l3) * (long)K + (l7 ^ l3) * 8;
  const unsigned ldsbase = (unsigned)(uintptr_t)&lds[0][0];
  const unsigned adst = wave * 1024u;            // bytes
  const unsigned bdst = 16384u + wave * 1024u;   // B region starts at 16KB

  #define STAGE(BUF, K0) { \
    unsigned bb = ldsbase + (unsigned)(BUF) * 49152u; \
    gload_lds16(asrc + (K0),                       bb + adst); \
    gload_lds16(asrc + 64 * (size_t)K + (K0),      bb + adst + 8192u); \
    gload_lds16(bsrc + (K0),                       bb + bdst); \
    gload_lds16(bsrc + 64 * (size_t)K + (K0),      bb + bdst + 8192u); \
    gload_lds16(bsrc + 128 * (size_t)K + (K0),     bb + bdst + 16384u); \
    gload_lds16(bsrc + 192 * (size_t)K + (K0),     bb + bdst + 24576u); \
  }

  f32x4 acc[4][4] = {};
  const int nk = K >> 6;
  int cur = 0;

  STAGE(0, 0)
  asm volatile("s_waitcnt vmcnt(0)" ::: "memory");
  __builtin_amdgcn_sched_barrier(0);
  __builtin_amdgcn_s_barrier();
  __builtin_amdgcn_sched_barrier(0);

  for (int t = 0; t < nk; ++t){
    if (t + 1 < nk){
      STAGE(cur ^ 1, (t + 1) * 64)
      asm volatile("s_waitcnt vmcnt(6)" ::: "memory");   // tile t landed, t+1 in flight
    } else {
      asm volatile("s_waitcnt vmcnt(0)" ::: "memory");
    }
    __builtin_amdgcn_sched_barrier(0);
    __builtin_amdgcn_s_barrier();
    __builtin_amdgcn_sched_barrier(0);

    const u16* Ab = &lds[cur][0];
    const u16* Bb = &lds[cur][8192];
    short8 af[2][4], bfr[2][4];
    #pragma unroll
    for (int kk = 0; kk < 2; kk++){
      #pragma unroll
      for (int m = 0; m < 4; m++){
        int row = wm * 64 + m * 16 + lr;
        int phys = (kk * 4 + lg) ^ (row & 7);
        af[kk][m] = *(const short8*)&Ab[row * 64 + phys * 8];
      }
      #pragma unroll
      for (int n = 0; n < 4; n++){
        int row = wn * 64 + n * 16 + lr;
        int phys = (kk * 4 + lg) ^ (row & 7);
        bfr[kk][n] = *(const short8*)&Bb[row * 64 + phys * 8];
      }
    }
    __builtin_amdgcn_s_setprio(1);
    #pragma unroll
    for (int m = 0; m < 4; m++)
      #pragma unroll
      for (int n = 0; n < 4; n++){
        acc[m][n] = __builtin_amdgcn_mfma_f32_16x16x32_bf16(af[0][m], bfr[0][n], acc[m][n], 0, 0, 0);
        acc[m][n] = __builtin_amdgcn_mfma_f32_16x16x32_bf16(af[1][m], bfr[1][n], acc[m][n], 0, 0, 0);
      }
    __builtin_amdgcn_s_setprio(0);

    __builtin_amdgcn_sched_barrier(0);
    __builtin_amdgcn_s_barrier();
    __builtin_amdgcn_sched_barrier(0);
    cur ^= 1;
  }
  #undef STAGE

  #pragma unroll
  for (int m = 0; m < 4; m++){
    #pragma unroll
    for (int n = 0; n < 4; n++){
      #pragma unroll
      for (int r = 0; r < 4; r++){
        long row = bm + wm*64 + m*16 + lg*4 + r;
        long col = bn + wn*64 + n*16 + lr;
        float v = acc[m][n][r];
        if (OUT_BF16) ((u16*)Cv)[row * (long)N + col] = f2bf(v);
        else          ((float*)Cv)[row * (long)N + col] = v;
      }
    }
  }
}

// ---------------- causal flash attention ----------------
// 512 thr = 8 waves; Q-tile 128 (16 rows/wave); KV-tile 64.
// Each block processes TWO q-tiles (qt = 15-pr then pr) -> uniform work.
__global__ __launch_bounds__(512, 2) void attn_fwd(const u16* __restrict__ qkv, u16* __restrict__ out){
  const int T = 2048, D3 = 6144, D = 2048, HD = 128;
  const int bh = blockIdx.x;
  const int pr = blockIdx.y;            // 0..7
  const int b = bh >> 4, h = bh & 15;
  const int tid = threadIdx.x, wave = tid >> 6, lane = tid & 63;
  const int lr = lane & 15, lg = lane >> 4;

  __shared__ u16 Klds[64][136];
  __shared__ u16 Vlds[64][136];
  __shared__ u16 Plds[8][16][72];

  const size_t base = (size_t)b * T * D3;
  const unsigned vtr = (unsigned)(uintptr_t)&Vlds[(lane >> 4) * 8 + ((lane >> 2) & 3)][(lane & 3) * 4];

  const int srow = tid >> 4;
  const int scol = (tid & 15) * 8;
  const u16* kgp = qkv + base + (size_t)srow * D3 + D + h * HD + scol;
  const u16* vgp = kgp + D;

  for (int half = 0; half < 2; half++){
    const int qt = half ? pr : (15 - pr);
    const int q0 = qt * 128;
    const int q0w = q0 + wave * 16;

    short8 qf[4];
    {
      const u16* qrow = qkv + base + (size_t)(q0w + lr) * D3 + h * HD;
      #pragma unroll
      for (int kk = 0; kk < 4; kk++)
        qf[kk] = *(const short8*)(qrow + kk*32 + lg*8);
    }

    f32x4 o[8] = {};
    float mrow[4], lrw[4];
    #pragma unroll
    for (int r = 0; r < 4; r++){ mrow[r] = -1e30f; lrw[r] = 0.f; }

    const int ntiles = (q0 + 128) >> 6;
    short8 kreg[2], vreg[2];
    #pragma unroll
    for (int c = 0; c < 2; c++){
      kreg[c] = *(const short8*)(kgp + (size_t)(32 * c) * D3);
      vreg[c] = *(const short8*)(vgp + (size_t)(32 * c) * D3);
    }

    for (int t = 0; t < ntiles; t++){
      const int k0 = t * 64;
      __syncthreads();
      #pragma unroll
      for (int c = 0; c < 2; c++){
        *(short8*)&Klds[srow + 32*c][scol] = kreg[c];
        *(short8*)&Vlds[srow + 32*c][scol] = vreg[c];
      }
      __syncthreads();
      if (t + 1 < ntiles){
        const u16* kn = kgp + (size_t)(k0 + 64) * D3;
        const u16* vn = vgp + (size_t)(k0 + 64) * D3;
        #pragma unroll
        for (int c = 0; c < 2; c++){
          kreg[c] = *(const short8*)(kn + (size_t)(32 * c) * D3);
          vreg[c] = *(const short8*)(vn + (size_t)(32 * c) * D3);
        }
      }

      if (k0 <= q0w + 15){
        f32x4 s[4] = {};
        #pragma unroll
        for (int kh = 0; kh < 4; kh++){
          #pragma unroll
          for (int kk = 0; kk < 4; kk++){
            short8 kfrag = *(const short8*)&Klds[kh*16 + lr][kk*32 + lg*8];
            s[kh] = __builtin_amdgcn_mfma_f32_16x16x32_bf16(qf[kk], kfrag, s[kh], 0, 0, 0);
          }
        }
        const float scale = 0.08838834764831845f;
        const bool need_mask = (k0 + 63 > q0w);
        #pragma unroll
        for (int kh = 0; kh < 4; kh++){
          int key = k0 + kh*16 + lr;
          #pragma unroll
          for (int r = 0; r < 4; r++){
            float v = s[kh][r] * scale;
            if (need_mask && key > q0w + lg*4 + r) v = -1e30f;
            s[kh][r] = v;
          }
        }
        float fs[4];
        #pragma unroll
        for (int r = 0; r < 4; r++){
          float mx = fmaxf(fmaxf(s[0][r], s[1][r]), fmaxf(s[2][r], s[3][r]));
          #pragma unroll
          for (int msk = 8; msk >= 1; msk >>= 1)
            mx = fmaxf(mx, __shfl_xor(mx, msk, 64));
          float mnew = fmaxf(mrow[r], mx);
          float f = __expf(mrow[r] - mnew);
          float p0 = __expf(s[0][r] - mnew);
          float p1 = __expf(s[1][r] - mnew);
          float p2 = __expf(s[2][r] - mnew);
          float p3 = __expf(s[3][r] - mnew);
          s[0][r] = p0; s[1][r] = p1; s[2][r] = p2; s[3][r] = p3;
          float rs = (p0 + p1) + (p2 + p3);
          #pragma unroll
          for (int msk = 8; msk >= 1; msk >>= 1)
            rs += __shfl_xor(rs, msk, 64);
          lrw[r] = lrw[r] * f + rs;
          mrow[r] = mnew;
          fs[r] = f;
        }
        #pragma unroll
        for (int dt = 0; dt < 8; dt++)
          #pragma unroll
          for (int r = 0; r < 4; r++)
            o[dt][r] *= fs[r];
        #pragma unroll
        for (int kh = 0; kh < 4; kh++)
          #pragma unroll
          for (int r = 0; r < 4; r++)
            Plds[wave][lg*4 + r][kh*16 + lr] = f2bf(s[kh][r]);
        asm volatile("s_waitcnt lgkmcnt(0)" ::: "memory");
        __builtin_amdgcn_sched_barrier(0);
        short8 pf[2];
        #pragma unroll
        for (int kp2 = 0; kp2 < 2; kp2++)
          pf[kp2] = *(const short8*)&Plds[wave][lr][kp2*32 + lg*8];
        asm volatile("s_waitcnt lgkmcnt(0)" ::: "memory");
        __builtin_amdgcn_sched_barrier(0);

        short4v vf[2][2][2];
        #define TR4(BUF, PTR) \
          asm volatile("ds_read_b64_tr_b16 %0, %1"             : "=v"(vf[BUF][0][0]) : "v"(PTR)); \
          asm volatile("ds_read_b64_tr_b16 %0, %1 offset:1088" : "=v"(vf[BUF][0][1]) : "v"(PTR)); \
          asm volatile("ds_read_b64_tr_b16 %0, %1 offset:8704" : "=v"(vf[BUF][1][0]) : "v"(PTR)); \
          asm volatile("ds_read_b64_tr_b16 %0, %1 offset:9792" : "=v"(vf[BUF][1][1]) : "v"(PTR));
        TR4(0, vtr)
        #pragma unroll
        for (int dt = 0; dt < 8; dt++){
          if (dt < 7){
            unsigned pn = vtr + (unsigned)((dt + 1) * 32);
            TR4((dt + 1) & 1, pn)
            asm volatile("s_waitcnt lgkmcnt(4)" ::: "memory");
          } else {
            asm volatile("s_waitcnt lgkmcnt(0)" ::: "memory");
          }
          __builtin_amdgcn_sched_barrier(0);
          short8 v0 = cat8(vf[dt & 1][0][0], vf[dt & 1][0][1]);
          short8 v1 = cat8(vf[dt & 1][1][0], vf[dt & 1][1][1]);
          o[dt] = __builtin_amdgcn_mfma_f32_16x16x32_bf16(pf[0], v0, o[dt], 0, 0, 0);
          o[dt] = __builtin_amdgcn_mfma_f32_16x16x32_bf16(pf[1], v1, o[dt], 0, 0, 0);
        }
        #undef TR4
      }
    }
    float rl[4];
    #pragma unroll
    for (int r = 0; r < 4; r++) rl[r] = 1.0f / lrw[r];
    #pragma unroll
    for (int dt = 0; dt < 8; dt++){
      #pragma unroll
      for (int r = 0; r < 4; r++){
        float v = o[dt][r] * rl[r];
        int qa = q0w + lg*4 + r;
        out[(size_t)(b * T + qa) * D + h * HD + dt*16 + lr] = f2bf(v);
      }
    }
  }
}

extern "C" void kernel_launch(void* const* d_in, const int* in_sizes, int n_in,
                              void* d_out, int out_size, void* d_ws, size_t ws_size,
                              hipStream_t stream) {
  const float* x    = (const float*)d_in[0];   // [2,2048,2048]
  const float* wqkv = (const float*)d_in[1];   // [6144,2048]
  const float* wout = (const float*)d_in[2];   // [2048,2048]
  float* out = (float*)d_out;                  // [2,2048,2048] f32

  u16* ws    = (u16*)d_ws;
  u16* xb    = ws;                    //  8,388,608 elems
  u16* wqkvb = xb + 8388608;          // 12,582,912 elems
  u16* qkvb  = wqkvb + 12582912;      // 25,165,824 elems
  u16* attnb = xb;                    // alias: x dead after GEMM1
  u16* woutb = wqkvb;                 // alias: wqkv dead after GEMM1

  cvt_bf16<<<2048, 256, 0, stream>>>(x,    xb,    8388608 / 4);
  cvt_bf16<<<2048, 256, 0, stream>>>(wqkv, wqkvb, 12582912 / 4);

  // qkv = x @ Wqkv^T : [4096][6144] bf16
  gemm_bt2<1><<<dim3(32, 24), 512, 0, stream>>>(xb, wqkvb, qkvb, 4096, 6144, 2048);

  cvt_bf16<<<2048, 256, 0, stream>>>(wout, woutb, 4194304 / 4);

  // attention: [4096][2048] bf16
  attn_fwd<<<dim3(32, 8), 512, 0, stream>>>(qkvb, attnb);

  // y = attn @ Wout^T : [4096][2048] f32
  gemm_bt2<0><<<dim3(32, 8), 512, 0, stream>>>(attnb, woutb, out, 4096, 2048, 2048);
}

// Round 6
// 266.312 us; speedup vs baseline: 1.7095x; 1.0082x over previous
//
#include <hip/hip_runtime.h>

typedef short short8 __attribute__((ext_vector_type(8)));
typedef short short4v __attribute__((ext_vector_type(4)));
typedef float f32x4 __attribute__((ext_vector_type(4)));
typedef unsigned short u16;
typedef u16 ushort4v __attribute__((ext_vector_type(4)));

__device__ inline u16 f2bf(float f){
  unsigned int u = __builtin_bit_cast(unsigned int, f);
  u = (u + 0x7fffu + ((u >> 16) & 1u)) >> 16;
  return (u16)u;
}

__device__ inline short8 cat8(short4v a, short4v b){
  short8 r;
  r[0]=a[0]; r[1]=a[1]; r[2]=a[2]; r[3]=a[3];
  r[4]=b[0]; r[5]=b[1]; r[6]=b[2]; r[7]=b[3];
  return r;
}

// async global->LDS, 16B per lane. lds dest = wave-uniform base + lane*16.
__device__ inline void gload_lds16(const void* g, unsigned lds_addr){
  __builtin_amdgcn_global_load_lds((__attribute__((address_space(1))) void*)(uintptr_t)g,
                                   (__attribute__((address_space(3))) void*)(uintptr_t)lds_addr,
                                   16, 0, 0);
}

// ---------------- f32 -> bf16 convert (vectorized) ----------------
__global__ void cvt_bf16(const float* __restrict__ in, u16* __restrict__ out, int n4){
  int stride = gridDim.x * blockDim.x;
  for (int i = blockIdx.x * blockDim.x + threadIdx.x; i < n4; i += stride){
    float4 v = ((const float4*)in)[i];
    ushort4v r = { f2bf(v.x), f2bf(v.y), f2bf(v.z), f2bf(v.w) };
    ((ushort4v*)out)[i] = r;
  }
}

// ================= 256x256 8-phase GEMM (m201-style) ======================
// C[M][N] = A[M][K] * B[N][K]^T. BK=64, 512 thr / 8 waves (2M x 4N),
// per-wave output 128x64 (acc[8][4]). LDS 128 KiB: 2 bufs x (A 256x64 | B 256x64).
// Per 2-K-tile iteration: 8 phases, each {ds_reads | 2 global_load_lds ->
// barrier -> setprio 16 MFMA setprio -> barrier}; vmcnt(4) at phases 4/8.
// Stage windows chosen so a buffer is written only after its reads drained.
#define BARRIER() { __builtin_amdgcn_sched_barrier(0); __builtin_amdgcn_s_barrier(); __builtin_amdgcn_sched_barrier(0); }
#define VM4() asm volatile("s_waitcnt vmcnt(4)" ::: "memory");

#define MFMA4(MO, AA, BB) { __builtin_amdgcn_s_setprio(1); \
  _Pragma("unroll") for (int m = 0; m < 4; m++) \
    _Pragma("unroll") for (int n = 0; n < 4; n++) \
      acc[(MO)+m][n] = __builtin_amdgcn_mfma_f32_16x16x32_bf16(AA[(MO)+m], BB[n], acc[(MO)+m][n], 0, 0, 0); \
  __builtin_amdgcn_s_setprio(0); }

#define PHASE4(ABASE, BBASE, ST1, ST2, ST3, ST4) { \
    const u16* Ab = (ABASE); const u16* Bb = (BBASE); \
    short8 a0[8], b0[4], a1[8], b1[4]; \
    _Pragma("unroll") for (int m = 0; m < 8; m++){ int row = wm*128 + m*16 + lr; int ph = lg ^ (row & 7); a0[m] = *(const short8*)&Ab[row*64 + ph*8]; } \
    _Pragma("unroll") for (int n = 0; n < 4; n++){ int row = wn*64 + n*16 + lr; int ph = lg ^ (row & 7); b0[n] = *(const short8*)&Bb[row*64 + ph*8]; } \
    ST1 BARRIER() MFMA4(0, a0, b0) BARRIER() \
    _Pragma("unroll") for (int m = 0; m < 8; m++){ int row = wm*128 + m*16 + lr; int ph = (4+lg) ^ (row & 7); a1[m] = *(const short8*)&Ab[row*64 + ph*8]; } \
    _Pragma("unroll") for (int n = 0; n < 4; n++){ int row = wn*64 + n*16 + lr; int ph = (4+lg) ^ (row & 7); b1[n] = *(const short8*)&Bb[row*64 + ph*8]; } \
    ST2 BARRIER() MFMA4(4, a0, b0) BARRIER() \
    ST3 BARRIER() MFMA4(0, a1, b1) BARRIER() \
    ST4 VM4() BARRIER() MFMA4(4, a1, b1) BARRIER() \
  }

template<int OUT_BF16>
__global__ __launch_bounds__(512, 2) void gemm256(const u16* __restrict__ A, const u16* __restrict__ B,
                                                  void* __restrict__ Cv, int M, int N, int K){
  __shared__ u16 lds[2][32768];   // per buf: A[256][64] @0, B[256][64] @16384 (elems)
  const int tid = threadIdx.x, wave = tid >> 6, lane = tid & 63;
  const int lr = lane & 15, lg = lane >> 4;
  const int wm = wave >> 2, wn = wave & 3;
  const long bm = blockIdx.x * 256L, bn = blockIdx.y * 256L;
  const int l3 = lane >> 3, l7 = lane & 7;

  // staging: sweep s covers rows s*64 + wave*8 + l3; phys 16B-slot = l7;
  // source col slot = l7 ^ (row&7) = l7 ^ l3 (inverse swizzle on the source).
  const u16* asrc = A + (bm + wave*8 + l3) * (long)K + (l7 ^ l3) * 8;
  const u16* bsrc = B + (bn + wave*8 + l3) * (long)K + (l7 ^ l3) * 8;
  const unsigned ldsbase = (unsigned)(uintptr_t)&lds[0][0];
  const unsigned wdst = wave * 1024u;

#define STG_A(BUF,S,KOFF) gload_lds16(asrc + (size_t)(S)*64*K + (KOFF), ldsbase + (BUF)*65536u + wdst + (S)*8192u);
#define STG_B(BUF,S,KOFF) gload_lds16(bsrc + (size_t)(S)*64*K + (KOFF), ldsbase + (BUF)*65536u + 32768u + wdst + (S)*8192u);

  f32x4 acc[8][4] = {};
  const int nk = K >> 6;          // 32 (even # of K-tiles required)

  // prologue: tile0 (A+B) -> buf0, tile1 A -> buf1 ; tile0 landed, 4 in flight
  #pragma unroll
  for (int s = 0; s < 4; s++){ STG_A(0, s, 0) }
  #pragma unroll
  for (int s = 0; s < 4; s++){ STG_B(0, s, 0) }
  #pragma unroll
  for (int s = 0; s < 4; s++){ STG_A(1, s, 64) }
  VM4()
  BARRIER()

  for (int i = 0; i < (nk >> 1); i++){
    const size_t kt1 = (size_t)((2*i + 1) << 6);
    const size_t kn0 = (size_t)(((2*i + 2) & (nk - 1)) << 6);
    const size_t kn1 = (size_t)(((2*i + 3) & (nk - 1)) << 6);
    // K-tile 2i in buf0; stages: P1,P2 finish tile 2i+1 B -> buf1 (buf1 B not
    // read until P5; landed-checked at P4's vmcnt). P3,P4: tile 2i+2 A -> buf0
    // (buf0 reads drained at P2).
    PHASE4(&lds[0][0], &lds[0][16384],
           STG_B(1,0,kt1) STG_B(1,1,kt1),
           STG_B(1,2,kt1) STG_B(1,3,kt1),
           STG_A(0,0,kn0) STG_A(0,1,kn0),
           STG_A(0,2,kn0) STG_A(0,3,kn0))
    // K-tile 2i+1 in buf1; stages: P5,P6 tile 2i+2 B -> buf0; P7,P8 tile 2i+3
    // A -> buf1 (buf1 reads drained at P6). vmcnt(4) at P8 => buf0 complete.
    PHASE4(&lds[1][0], &lds[1][16384],
           STG_B(0,0,kn0) STG_B(0,1,kn0),
           STG_B(0,2,kn0) STG_B(0,3,kn0),
           STG_A(1,0,kn1) STG_A(1,1,kn1),
           STG_A(1,2,kn1) STG_A(1,3,kn1))
  }
#undef STG_A
#undef STG_B

  #pragma unroll
  for (int m = 0; m < 8; m++){
    #pragma unroll
    for (int n = 0; n < 4; n++){
      #pragma unroll
      for (int r = 0; r < 4; r++){
        long row = bm + wm*128 + m*16 + lg*4 + r;
        long col = bn + wn*64 + n*16 + lr;
        float v = acc[m][n][r];
        if (OUT_BF16) ((u16*)Cv)[row * (long)N + col] = f2bf(v);
        else          ((float*)Cv)[row * (long)N + col] = v;
      }
    }
  }
}

// ---------------- 128x256 2-phase GEMM (kept for GEMM2: 256-block grid) ----
template<int OUT_BF16>
__global__ __launch_bounds__(512, 2) void gemm_bt2(const u16* __restrict__ A, const u16* __restrict__ B,
                                                   void* __restrict__ Cv, int M, int N, int K){
  __shared__ u16 lds[2][24576];   // per buf: A 128x64 (8192) then B 256x64 (16384)
  const int tid = threadIdx.x, wave = tid >> 6, lane = tid & 63;
  const int lr = lane & 15, lg = lane >> 4;
  const int wm = wave >> 2, wn = wave & 3;
  const long bm = blockIdx.x * 128L, bn = blockIdx.y * 256L;
  const int l3 = lane >> 3, l7 = lane & 7;

  const u16* asrc = A + (bm + wave * 8 + l3) * (long)K + (l7 ^ l3) * 8;
  const u16* bsrc = B + (bn + wave * 8 + l3) * (long)K + (l7 ^ l3) * 8;
  const unsigned ldsbase = (unsigned)(uintptr_t)&lds[0][0];
  const unsigned adst = wave * 1024u;
  const unsigned bdst = 16384u + wave * 1024u;

  #define STAGE(BUF, K0) { \
    unsigned bb = ldsbase + (unsigned)(BUF) * 49152u; \
    gload_lds16(asrc + (K0),                       bb + adst); \
    gload_lds16(asrc + 64 * (size_t)K + (K0),      bb + adst + 8192u); \
    gload_lds16(bsrc + (K0),                       bb + bdst); \
    gload_lds16(bsrc + 64 * (size_t)K + (K0),      bb + bdst + 8192u); \
    gload_lds16(bsrc + 128 * (size_t)K + (K0),     bb + bdst + 16384u); \
    gload_lds16(bsrc + 192 * (size_t)K + (K0),     bb + bdst + 24576u); \
  }

  f32x4 acc[4][4] = {};
  const int nk = K >> 6;
  int cur = 0;

  STAGE(0, 0)
  asm volatile("s_waitcnt vmcnt(0)" ::: "memory");
  BARRIER()

  for (int t = 0; t < nk; ++t){
    if (t + 1 < nk){
      STAGE(cur ^ 1, (t + 1) * 64)
      asm volatile("s_waitcnt vmcnt(6)" ::: "memory");
    } else {
      asm volatile("s_waitcnt vmcnt(0)" ::: "memory");
    }
    BARRIER()

    const u16* Ab = &lds[cur][0];
    const u16* Bb = &lds[cur][8192];
    short8 af[2][4], bfr[2][4];
    #pragma unroll
    for (int kk = 0; kk < 2; kk++){
      #pragma unroll
      for (int m = 0; m < 4; m++){
        int row = wm * 64 + m * 16 + lr;
        int phys = (kk * 4 + lg) ^ (row & 7);
        af[kk][m] = *(const short8*)&Ab[row * 64 + phys * 8];
      }
      #pragma unroll
      for (int n = 0; n < 4; n++){
        int row = wn * 64 + n * 16 + lr;
        int phys = (kk * 4 + lg) ^ (row & 7);
        bfr[kk][n] = *(const short8*)&Bb[row * 64 + phys * 8];
      }
    }
    __builtin_amdgcn_s_setprio(1);
    #pragma unroll
    for (int m = 0; m < 4; m++)
      #pragma unroll
      for (int n = 0; n < 4; n++){
        acc[m][n] = __builtin_amdgcn_mfma_f32_16x16x32_bf16(af[0][m], bfr[0][n], acc[m][n], 0, 0, 0);
        acc[m][n] = __builtin_amdgcn_mfma_f32_16x16x32_bf16(af[1][m], bfr[1][n], acc[m][n], 0, 0, 0);
      }
    __builtin_amdgcn_s_setprio(0);
    BARRIER()
    cur ^= 1;
  }
  #undef STAGE

  #pragma unroll
  for (int m = 0; m < 4; m++){
    #pragma unroll
    for (int n = 0; n < 4; n++){
      #pragma unroll
      for (int r = 0; r < 4; r++){
        long row = bm + wm*64 + m*16 + lg*4 + r;
        long col = bn + wn*64 + n*16 + lr;
        float v = acc[m][n][r];
        if (OUT_BF16) ((u16*)Cv)[row * (long)N + col] = f2bf(v);
        else          ((float*)Cv)[row * (long)N + col] = v;
      }
    }
  }
}

// ---------------- causal flash attention ----------------
__global__ __launch_bounds__(512, 2) void attn_fwd(const u16* __restrict__ qkv, u16* __restrict__ out){
  const int T = 2048, D3 = 6144, D = 2048, HD = 128;
  const int bh = blockIdx.x;
  const int pr = blockIdx.y;            // 0..7
  const int b = bh >> 4, h = bh & 15;
  const int tid = threadIdx.x, wave = tid >> 6, lane = tid & 63;
  const int lr = lane & 15, lg = lane >> 4;

  __shared__ u16 Klds[64][136];
  __shared__ u16 Vlds[64][136];
  __shared__ u16 Plds[8][16][72];

  const size_t base = (size_t)b * T * D3;
  const unsigned vtr = (unsigned)(uintptr_t)&Vlds[(lane >> 4) * 8 + ((lane >> 2) & 3)][(lane & 3) * 4];

  const int srow = tid >> 4;
  const int scol = (tid & 15) * 8;
  const u16* kgp = qkv + base + (size_t)srow * D3 + D + h * HD + scol;
  const u16* vgp = kgp + D;

  for (int half = 0; half < 2; half++){
    const int qt = half ? pr : (15 - pr);
    const int q0 = qt * 128;
    const int q0w = q0 + wave * 16;

    short8 qf[4];
    {
      const u16* qrow = qkv + base + (size_t)(q0w + lr) * D3 + h * HD;
      #pragma unroll
      for (int kk = 0; kk < 4; kk++)
        qf[kk] = *(const short8*)(qrow + kk*32 + lg*8);
    }

    f32x4 o[8] = {};
    float mrow[4], lrw[4];
    #pragma unroll
    for (int r = 0; r < 4; r++){ mrow[r] = -1e30f; lrw[r] = 0.f; }

    const int ntiles = (q0 + 128) >> 6;
    short8 kreg[2], vreg[2];
    #pragma unroll
    for (int c = 0; c < 2; c++){
      kreg[c] = *(const short8*)(kgp + (size_t)(32 * c) * D3);
      vreg[c] = *(const short8*)(vgp + (size_t)(32 * c) * D3);
    }

    for (int t = 0; t < ntiles; t++){
      const int k0 = t * 64;
      __syncthreads();
      #pragma unroll
      for (int c = 0; c < 2; c++){
        *(short8*)&Klds[srow + 32*c][scol] = kreg[c];
        *(short8*)&Vlds[srow + 32*c][scol] = vreg[c];
      }
      __syncthreads();
      if (t + 1 < ntiles){
        const u16* kn = kgp + (size_t)(k0 + 64) * D3;
        const u16* vn = vgp + (size_t)(k0 + 64) * D3;
        #pragma unroll
        for (int c = 0; c < 2; c++){
          kreg[c] = *(const short8*)(kn + (size_t)(32 * c) * D3);
          vreg[c] = *(const short8*)(vn + (size_t)(32 * c) * D3);
        }
      }

      if (k0 <= q0w + 15){
        f32x4 s[4] = {};
        #pragma unroll
        for (int kh = 0; kh < 4; kh++){
          #pragma unroll
          for (int kk = 0; kk < 4; kk++){
            short8 kfrag = *(const short8*)&Klds[kh*16 + lr][kk*32 + lg*8];
            s[kh] = __builtin_amdgcn_mfma_f32_16x16x32_bf16(qf[kk], kfrag, s[kh], 0, 0, 0);
          }
        }
        const float scale = 0.08838834764831845f;
        const bool need_mask = (k0 + 63 > q0w);
        #pragma unroll
        for (int kh = 0; kh < 4; kh++){
          int key = k0 + kh*16 + lr;
          #pragma unroll
          for (int r = 0; r < 4; r++){
            float v = s[kh][r] * scale;
            if (need_mask && key > q0w + lg*4 + r) v = -1e30f;
            s[kh][r] = v;
          }
        }
        float fs[4];
        #pragma unroll
        for (int r = 0; r < 4; r++){
          float mx = fmaxf(fmaxf(s[0][r], s[1][r]), fmaxf(s[2][r], s[3][r]));
          #pragma unroll
          for (int msk = 8; msk >= 1; msk >>= 1)
            mx = fmaxf(mx, __shfl_xor(mx, msk, 64));
          float mnew = fmaxf(mrow[r], mx);
          float f = __expf(mrow[r] - mnew);
          float p0 = __expf(s[0][r] - mnew);
          float p1 = __expf(s[1][r] - mnew);
          float p2 = __expf(s[2][r] - mnew);
          float p3 = __expf(s[3][r] - mnew);
          s[0][r] = p0; s[1][r] = p1; s[2][r] = p2; s[3][r] = p3;
          float rs = (p0 + p1) + (p2 + p3);
          #pragma unroll
          for (int msk = 8; msk >= 1; msk >>= 1)
            rs += __shfl_xor(rs, msk, 64);
          lrw[r] = lrw[r] * f + rs;
          mrow[r] = mnew;
          fs[r] = f;
        }
        #pragma unroll
        for (int dt = 0; dt < 8; dt++)
          #pragma unroll
          for (int r = 0; r < 4; r++)
            o[dt][r] *= fs[r];
        #pragma unroll
        for (int kh = 0; kh < 4; kh++)
          #pragma unroll
          for (int r = 0; r < 4; r++)
            Plds[wave][lg*4 + r][kh*16 + lr] = f2bf(s[kh][r]);
        asm volatile("s_waitcnt lgkmcnt(0)" ::: "memory");
        __builtin_amdgcn_sched_barrier(0);
        short8 pf[2];
        #pragma unroll
        for (int kp2 = 0; kp2 < 2; kp2++)
          pf[kp2] = *(const short8*)&Plds[wave][lr][kp2*32 + lg*8];
        asm volatile("s_waitcnt lgkmcnt(0)" ::: "memory");
        __builtin_amdgcn_sched_barrier(0);

        short4v vf[2][2][2];
        #define TR4(BUF, PTR) \
          asm volatile("ds_read_b64_tr_b16 %0, %1"             : "=v"(vf[BUF][0][0]) : "v"(PTR)); \
          asm volatile("ds_read_b64_tr_b16 %0, %1 offset:1088" : "=v"(vf[BUF][0][1]) : "v"(PTR)); \
          asm volatile("ds_read_b64_tr_b16 %0, %1 offset:8704" : "=v"(vf[BUF][1][0]) : "v"(PTR)); \
          asm volatile("ds_read_b64_tr_b16 %0, %1 offset:9792" : "=v"(vf[BUF][1][1]) : "v"(PTR));
        TR4(0, vtr)
        #pragma unroll
        for (int dt = 0; dt < 8; dt++){
          if (dt < 7){
            unsigned pn = vtr + (unsigned)((dt + 1) * 32);
            TR4((dt + 1) & 1, pn)
            asm volatile("s_waitcnt lgkmcnt(4)" ::: "memory");
          } else {
            asm volatile("s_waitcnt lgkmcnt(0)" ::: "memory");
          }
          __builtin_amdgcn_sched_barrier(0);
          short8 v0 = cat8(vf[dt & 1][0][0], vf[dt & 1][0][1]);
          short8 v1 = cat8(vf[dt & 1][1][0], vf[dt & 1][1][1]);
          o[dt] = __builtin_amdgcn_mfma_f32_16x16x32_bf16(pf[0], v0, o[dt], 0, 0, 0);
          o[dt] = __builtin_amdgcn_mfma_f32_16x16x32_bf16(pf[1], v1, o[dt], 0, 0, 0);
        }
        #undef TR4
      }
    }
    float rl[4];
    #pragma unroll
    for (int r = 0; r < 4; r++) rl[r] = 1.0f / lrw[r];
    #pragma unroll
    for (int dt = 0; dt < 8; dt++){
      #pragma unroll
      for (int r = 0; r < 4; r++){
        float v = o[dt][r] * rl[r];
        int qa = q0w + lg*4 + r;
        out[(size_t)(b * T + qa) * D + h * HD + dt*16 + lr] = f2bf(v);
      }
    }
  }
}

extern "C" void kernel_launch(void* const* d_in, const int* in_sizes, int n_in,
                              void* d_out, int out_size, void* d_ws, size_t ws_size,
                              hipStream_t stream) {
  const float* x    = (const float*)d_in[0];   // [2,2048,2048]
  const float* wqkv = (const float*)d_in[1];   // [6144,2048]
  const float* wout = (const float*)d_in[2];   // [2048,2048]
  float* out = (float*)d_out;                  // [2,2048,2048] f32

  u16* ws    = (u16*)d_ws;
  u16* xb    = ws;                    //  8,388,608 elems
  u16* wqkvb = xb + 8388608;          // 12,582,912 elems
  u16* qkvb  = wqkvb + 12582912;      // 25,165,824 elems
  u16* attnb = xb;                    // alias: x dead after GEMM1
  u16* woutb = wqkvb;                 // alias: wqkv dead after GEMM1

  cvt_bf16<<<2048, 256, 0, stream>>>(x,    xb,    8388608 / 4);
  cvt_bf16<<<2048, 256, 0, stream>>>(wqkv, wqkvb, 12582912 / 4);

  // qkv = x @ Wqkv^T : [4096][6144] bf16  (256^2 8-phase, 16x24 = 384 blocks)
  gemm256<1><<<dim3(16, 24), 512, 0, stream>>>(xb, wqkvb, qkvb, 4096, 6144, 2048);

  cvt_bf16<<<2048, 256, 0, stream>>>(wout, woutb, 4194304 / 4);

  // attention: [4096][2048] bf16
  attn_fwd<<<dim3(32, 8), 512, 0, stream>>>(qkvb, attnb);

  // y = attn @ Wout^T : [4096][2048] f32  (128x256, 32x8 = 256 blocks)
  gemm_bt2<0><<<dim3(32, 8), 512, 0, stream>>>(attnb, woutb, out, 4096, 2048, 2048);
}